// Round 4
// baseline (432.793 us; speedup 1.0000x reference)
//
#include <hip/hip_runtime.h>

typedef __bf16 bf16;
typedef unsigned int u32;
typedef __attribute__((ext_vector_type(4))) float f32x4;
typedef __attribute__((ext_vector_type(8))) __bf16 bf16x8;
typedef __attribute__((ext_vector_type(4))) __bf16 bf16x4;

#define MFMA_(a, b, c) __builtin_amdgcn_mfma_f32_16x16x32_bf16((a), (b), (c), 0, 0, 0)

#define DIN 4096
#define DOUT 4096
#define DR 512

__device__ __forceinline__ void gll16(const void* g, void* l) {
  __builtin_amdgcn_global_load_lds((const __attribute__((address_space(1))) u32*)g,
                                   (__attribute__((address_space(3))) u32*)l, 16, 0, 0);
}

#define FENCE() asm volatile("" ::: "memory")
#define SCHEDB() __builtin_amdgcn_sched_barrier(0)
#define WAITVM(n) do { SCHEDB(); asm volatile("s_waitcnt vmcnt(" #n ")" ::: "memory"); } while (0)
#define WAITLGKM0() asm volatile("s_waitcnt lgkmcnt(0)" ::: "memory")
#define BARRIER() do { FENCE(); __builtin_amdgcn_s_barrier(); SCHEDB(); } while (0)

// ---------------- prep: V -> bf16 [512][4096] ----------------
__global__ __launch_bounds__(256) void prep_v_kernel(const float* __restrict__ vt,
                                                     const float* __restrict__ vd,
                                                     bf16* __restrict__ Vb) {
  int idx = blockIdx.x * 256 + threadIdx.x;
  int e = idx * 4;
  int r = e >> 12, c = e & 4095;
  const float* src = (r < 64) ? (vt + ((size_t)r << 12) + c) : (vd + ((size_t)(r - 64) << 12) + c);
  float4 v = *reinterpret_cast<const float4*>(src);
  bf16x4 o = {(bf16)v.x, (bf16)v.y, (bf16)v.z, (bf16)v.w};
  *reinterpret_cast<bf16x4*>(Vb + e) = o;
}

// ---------------- prep: (U * s) -> bf16 [4096][512] ----------------
__global__ __launch_bounds__(256) void prep_u_kernel(const float* __restrict__ ut,
                                                     const float* __restrict__ ud,
                                                     const float* __restrict__ s,
                                                     bf16* __restrict__ Ub) {
  int idx = blockIdx.x * 256 + threadIdx.x;
  int o = idx >> 7;
  int rr = (idx & 127) * 4;
  const float* src = (rr < 64) ? (ut + (size_t)o * 64 + rr) : (ud + (size_t)o * 448 + (rr - 64));
  float4 v = *reinterpret_cast<const float4*>(src);
  float4 sv = *reinterpret_cast<const float4*>(s + rr);
  bf16x4 ov = {(bf16)(v.x * sv.x), (bf16)(v.y * sv.y), (bf16)(v.z * sv.z), (bf16)(v.w * sv.w)};
  *reinterpret_cast<bf16x4*>(Ub + (size_t)o * DR + rr) = ov;
}

// ---------------- GEMM1: t[8192][512] = x[8192][4096] * Vb[512][4096]^T ----------------
// BM=64 BN=512(full N) BK=32, 512 thr (8 waves 2Mx4N, wave 32x128), grid 128.
// Each X panel read by exactly ONE block (X crosses fabric once); all blocks read
// the same 32KB Vb slice per iter (Vb L2-resident). 4 LDS bufs, 2-deep prefetch,
// counted vmcnt(10) [5 VM ops/wave/iter], one raw barrier/iter.
__global__ __launch_bounds__(512) void gemm1_kernel(const float* __restrict__ X,
                                                    const bf16* __restrict__ Vb,
                                                    bf16* __restrict__ T) {
  __shared__ alignas(16) bf16 As[4 * 2048];   // 4 bufs x [64 rows][4 slots of 8]  (16 KB)
  __shared__ alignas(16) bf16 Bs[4 * 16384];  // 4 bufs x [512 rows][4 slots of 8] (128 KB)

  const int tid = threadIdx.x;
  const int m0 = blockIdx.x * 64;  // no swizzle needed: X private per block, Vb shared by all

  const int wid = tid >> 6, lane = tid & 63;
  const int wr = wid >> 2, wc = wid & 3;  // 2x4 wave grid; wave tile 32x128
  const int lr = lane & 15, kg = lane >> 4;
  const int ksw = kg ^ ((lr >> 1) & 3);  // phys k-slot for frag reads (verified involution)

  // A staging: 512 thr x 1 float4; row = tid>>3, q = tid&7 -> logical slot s=q>>1, half h=q&1
  const int arow = tid >> 3, aq = tid & 7;
  const int as_ = aq >> 1, ah = aq & 1;
  const int aphys = as_ ^ ((arow >> 1) & 3);
  const float* aG = X + (size_t)(m0 + arow) * DIN + aq * 4;
  const int awoff = arow * 32 + aphys * 8 + ah * 4;

  // B staging: 32 chunks of 16 rows; wave wid owns chunks wid*4..wid*4+3.
  // Linear LDS dest (elem = row*32 + p*8, p=lane&3); source k-slot pre-swizzled.
  const int srcsl = (lane & 3) ^ ((lane >> 3) & 3);
  const int rl = lane >> 2;
  const bf16* bG[4];
  int bL[4];
#pragma unroll
  for (int i = 0; i < 4; ++i) {
    const int c = wid * 4 + i;
    bG[i] = Vb + (size_t)(c * 16 + rl) * DIN + srcsl * 8;
    bL[i] = c * 512;
  }

  int aoff[2], boff[8];
#pragma unroll
  for (int mi = 0; mi < 2; ++mi) aoff[mi] = (wr * 32 + mi * 16 + lr) * 32 + ksw * 8;
#pragma unroll
  for (int ni = 0; ni < 8; ++ni) boff[ni] = (wc * 128 + ni * 16 + lr) * 32 + ksw * 8;

  f32x4 acc[2][8];
  const f32x4 z = {0.f, 0.f, 0.f, 0.f};
#pragma unroll
  for (int i = 0; i < 2; ++i)
#pragma unroll
    for (int j = 0; j < 8; ++j) acc[i][j] = z;

  float4 rA[4];

  // ---- prologue: queue = A0 | B0x4 | A1 | B1x4 | A2 ----
  rA[0] = *reinterpret_cast<const float4*>(aG);
  SCHEDB();
#pragma unroll
  for (int i = 0; i < 4; ++i) gll16(bG[i], &Bs[0 * 16384 + bL[i]]);
  SCHEDB();
  rA[1] = *reinterpret_cast<const float4*>(aG + 32);
  SCHEDB();
#pragma unroll
  for (int i = 0; i < 4; ++i) gll16(bG[i] + 32, &Bs[1 * 16384 + bL[i]]);
  SCHEDB();
  rA[2] = *reinterpret_cast<const float4*>(aG + 64);
  WAITVM(10);  // A0 landed
  {
    float4 v = rA[0];
    bf16x4 w = {(bf16)v.x, (bf16)v.y, (bf16)v.z, (bf16)v.w};
    *reinterpret_cast<bf16x4*>(&As[0 * 2048 + awoff]) = w;
  }

#define G1_BODY(t, RB, WB, PB, SW, SP)                                               \
  do {                                                                               \
    const int kt2 = ((t) + 2 < 128) ? (t) + 2 : 127;                                 \
    const int kt3 = ((t) + 3 < 128) ? (t) + 3 : 127;                                 \
    _Pragma("unroll") for (int i = 0; i < 4; ++i)                                    \
        gll16(bG[i] + (size_t)kt2 * 32, &Bs[(PB) * 16384 + bL[i]]);                  \
    rA[SP] = *reinterpret_cast<const float4*>(aG + (size_t)kt3 * 32);                \
    WAITVM(10); /* B(t)x4, A(t+1) landed */                                          \
    {                                                                                \
      float4 v = rA[SW];                                                             \
      bf16x4 w = {(bf16)v.x, (bf16)v.y, (bf16)v.z, (bf16)v.w};                       \
      *reinterpret_cast<bf16x4*>(&As[(WB) * 2048 + awoff]) = w;                      \
    }                                                                                \
    WAITLGKM0();                                                                     \
    BARRIER();                                                                       \
    bf16x8 afr[2], bfr[8];                                                           \
    _Pragma("unroll") for (int mi = 0; mi < 2; ++mi)                                 \
        afr[mi] = *reinterpret_cast<const bf16x8*>(&As[(RB) * 2048 + aoff[mi]]);     \
    _Pragma("unroll") for (int ni = 0; ni < 8; ++ni)                                 \
        bfr[ni] = *reinterpret_cast<const bf16x8*>(&Bs[(RB) * 16384 + boff[ni]]);    \
    _Pragma("unroll") for (int mi = 0; mi < 2; ++mi)                                 \
        _Pragma("unroll") for (int ni = 0; ni < 8; ++ni)                             \
            acc[mi][ni] = MFMA_(afr[mi], bfr[ni], acc[mi][ni]);                      \
  } while (0)

  for (int tb = 0; tb < 128; tb += 4) {
    G1_BODY(tb + 0, 0, 1, 2, 1, 3);
    G1_BODY(tb + 1, 1, 2, 3, 2, 0);
    G1_BODY(tb + 2, 2, 3, 0, 3, 1);
    G1_BODY(tb + 3, 3, 0, 1, 0, 2);
  }
#undef G1_BODY

  // epilogue: C/D layout col = lane&15, row = (lane>>4)*4 + j
#pragma unroll
  for (int mi = 0; mi < 2; ++mi) {
    const int rbase = m0 + wr * 32 + mi * 16 + kg * 4;
#pragma unroll
    for (int ni = 0; ni < 8; ++ni) {
      const int c = wc * 128 + ni * 16 + lr;
      f32x4 a = acc[mi][ni];
#pragma unroll
      for (int j = 0; j < 4; ++j)
        T[(size_t)(rbase + j) * DR + c] = (bf16)a[j];
    }
  }
}

// ---------------- GEMM2: out[8192][4096] = t[8192][512] * Ub[4096][512]^T + bias ----------------
// BM=128 BN=128 BK=32, 256 thr (4 waves 2x2, wave 64x64). 4 LDS bufs, 2-deep
// prefetch, counted vmcnt(8), one raw barrier/iter. nt-partitioned XCD mapping:
// each XCD owns 4 nt (Ub 2MB L2-resident) x all 64 mt, mt-major (T streamed once/XCD).
__global__ __launch_bounds__(256) void gemm2_kernel(const bf16* __restrict__ Tt,
                                                    const bf16* __restrict__ Ub,
                                                    const float* __restrict__ bias,
                                                    float* __restrict__ Out) {
  __shared__ alignas(16) bf16 As[4 * 4096];
  __shared__ alignas(16) bf16 Bs[4 * 4096];

  const int tid = threadIdx.x;
  const int xcd = blockIdx.x & 7;
  const int idx = blockIdx.x >> 3;
  const int nt = xcd * 4 + (idx & 3);  // XCD owns 4 consecutive nt
  const int mt = idx >> 2;             // mt-major within XCD
  const int m0 = mt * 128, n0 = nt * 128;

  const int wid = tid >> 6, lane = tid & 63;
  const int wr = wid >> 1, wc = wid & 1;
  const int lr = lane & 15, kg = lane >> 4;
  const int ks = kg ^ ((lr >> 1) & 3);

  const int c0 = wid * 2, c1 = wid * 2 + 1;
  const int srcsl = (lane & 3) ^ ((lane >> 3) & 3);
  const bf16* aG0 = Tt + (size_t)(m0 + c0 * 16 + (lane >> 2)) * DR + srcsl * 8;
  const bf16* aG1 = Tt + (size_t)(m0 + c1 * 16 + (lane >> 2)) * DR + srcsl * 8;
  const bf16* bG0 = Ub + (size_t)(n0 + c0 * 16 + (lane >> 2)) * DR + srcsl * 8;
  const bf16* bG1 = Ub + (size_t)(n0 + c1 * 16 + (lane >> 2)) * DR + srcsl * 8;

  int aoff[4], boff[4];
#pragma unroll
  for (int mi = 0; mi < 4; ++mi) aoff[mi] = ((wr * 64 + mi * 16 + lr) * 4 + ks) * 8;
#pragma unroll
  for (int ni = 0; ni < 4; ++ni) boff[ni] = ((wc * 64 + ni * 16 + lr) * 4 + ks) * 8;

  f32x4 acc[4][4];
  const f32x4 z = {0.f, 0.f, 0.f, 0.f};
#pragma unroll
  for (int i = 0; i < 4; ++i)
#pragma unroll
    for (int j = 0; j < 4; ++j) acc[i][j] = z;

  // ---- prologue: S(0) | S(1) ----
  gll16(aG0, &As[0 * 4096 + c0 * 512]);
  gll16(aG1, &As[0 * 4096 + c1 * 512]);
  gll16(bG0, &Bs[0 * 4096 + c0 * 512]);
  gll16(bG1, &Bs[0 * 4096 + c1 * 512]);
  SCHEDB();
  gll16(aG0 + 32, &As[1 * 4096 + c0 * 512]);
  gll16(aG1 + 32, &As[1 * 4096 + c1 * 512]);
  gll16(bG0 + 32, &Bs[1 * 4096 + c0 * 512]);
  gll16(bG1 + 32, &Bs[1 * 4096 + c1 * 512]);
  SCHEDB();

#define G2_BODY(t, RB, PB)                                                           \
  do {                                                                               \
    const int kt2 = ((t) + 2 < 16) ? (t) + 2 : 15;                                   \
    gll16(aG0 + (size_t)kt2 * 32, &As[(PB) * 4096 + c0 * 512]);                      \
    gll16(aG1 + (size_t)kt2 * 32, &As[(PB) * 4096 + c1 * 512]);                      \
    gll16(bG0 + (size_t)kt2 * 32, &Bs[(PB) * 4096 + c0 * 512]);                      \
    gll16(bG1 + (size_t)kt2 * 32, &Bs[(PB) * 4096 + c1 * 512]);                      \
    WAITVM(8); /* S(t) landed */                                                     \
    BARRIER();                                                                       \
    bf16x8 afr[4], bfr[4];                                                           \
    _Pragma("unroll") for (int mi = 0; mi < 4; ++mi)                                 \
        afr[mi] = *reinterpret_cast<const bf16x8*>(&As[(RB) * 4096 + aoff[mi]]);     \
    _Pragma("unroll") for (int ni = 0; ni < 4; ++ni)                                 \
        bfr[ni] = *reinterpret_cast<const bf16x8*>(&Bs[(RB) * 4096 + boff[ni]]);     \
    _Pragma("unroll") for (int mi = 0; mi < 4; ++mi)                                 \
        _Pragma("unroll") for (int ni = 0; ni < 4; ++ni)                             \
            acc[mi][ni] = MFMA_(afr[mi], bfr[ni], acc[mi][ni]);                      \
  } while (0)

  for (int tb = 0; tb < 16; tb += 4) {
    G2_BODY(tb + 0, 0, 2);
    G2_BODY(tb + 1, 1, 3);
    G2_BODY(tb + 2, 2, 0);
    G2_BODY(tb + 3, 3, 1);
  }
#undef G2_BODY

#pragma unroll
  for (int ni = 0; ni < 4; ++ni) {
    const int c = n0 + wc * 64 + ni * 16 + lr;
    const float bv = bias[c];
#pragma unroll
    for (int mi = 0; mi < 4; ++mi) {
      const int rbase = m0 + wr * 64 + mi * 16 + kg * 4;
      f32x4 a = acc[mi][ni];
#pragma unroll
      for (int j = 0; j < 4; ++j)
        Out[(size_t)(rbase + j) * DOUT + c] = a[j] + bv;
    }
  }
}

extern "C" void kernel_launch(void* const* d_in, const int* in_sizes, int n_in,
                              void* d_out, int out_size, void* d_ws, size_t ws_size,
                              hipStream_t stream) {
  const float* x = (const float*)d_in[0];
  const float* u_t = (const float*)d_in[1];
  const float* s = (const float*)d_in[2];
  const float* v_t = (const float*)d_in[3];
  const float* u_d = (const float*)d_in[4];
  const float* v_d = (const float*)d_in[5];
  const float* bias = (const float*)d_in[6];
  float* out = (float*)d_out;

  bf16* Vb = (bf16*)d_ws;                        // 4 MiB: [512][4096]
  bf16* Ub = (bf16*)((char*)d_ws + (4u << 20));  // 4 MiB: [4096][512]
  bf16* T = (bf16*)((char*)d_ws + (8u << 20));   // 8 MiB: [8192][512]

  hipLaunchKernelGGL(prep_v_kernel, dim3(2048), dim3(256), 0, stream, v_t, v_d, Vb);
  hipLaunchKernelGGL(prep_u_kernel, dim3(2048), dim3(256), 0, stream, u_t, u_d, s, Ub);
  hipLaunchKernelGGL(gemm1_kernel, dim3(128), dim3(512), 0, stream, x, Vb, T);
  hipLaunchKernelGGL(gemm2_kernel, dim3(2048), dim3(256), 0, stream, T, Ub, bias, out);
}